// Round 9
// baseline (2280.800 us; speedup 1.0000x reference)
//
#include <hip/hip_runtime.h>
#include <hip/hip_bf16.h>
#include <stdint.h>

// AFT-full, MI355X. Shapes: x[64,1024,512], W*[512,512], pos_bias[1024,1024].
//   q,k,v = x W^T + b ; out = sigmoid(q) * (eb@(e^k*v)) / (eb@e^k), eb=exp(pos_bias)
// Pipeline:
//   K0: eb = bf16(exp(pos_bias));  K1: xb = bf16(x), Wb = [Wq; Wk/Wv interleaved]
//   P1: fused QKV GEMM -> s (sigmoid(q), natural), Z (ekv/ek K-major interleaved)
//   P2: merged GEMM C[i,n] = eb @ Z^T, register-local num/den division epilogue.
// r9: occupancy-2 K-loop. 256x256 tile, BK=32, 8 waves, LDS = 2 slots x 32 KiB
// (A+B) = 64 KiB -> 2 blocks/CU, 4 waves/SIMD (launch_bounds(512,4)). Per tile:
// {stage(t+1) first (8 gl_lds) | 12 ds_read | 32 MFMA | vmcnt(0) | barrier} —
// the wait targets loads issued a full tile earlier; residue + per-block
// prologue/epilogue hide under the co-resident block (m114 mechanism).
// Paired-row LDS layout (bank-conflict-free, r7-verified): (r,c) at
// (r>>1)*64 + (r&1)*32 + ((c>>3)^((r>>1)&3))*8 shorts; stage pre-applies the
// inverse permutation on the global source (both-sides rule).
// Workspace: eb 2MiB@0, Wb 1.5MiB@2MiB, xb 64MiB@4MiB, s 64MiB@68MiB, Z 128MiB@132MiB.

#define NSEQ 1024
#define DM   512

typedef __attribute__((ext_vector_type(8))) short bf16x8;
typedef __attribute__((ext_vector_type(4))) float f32x4;

static __device__ __forceinline__ float b2f(unsigned short u) {
    union { uint32_t i; float f; } c; c.i = ((uint32_t)u) << 16; return c.f;
}
static __device__ __forceinline__ unsigned short f2b(float f) {
    union { float f; uint32_t i; } c; c.f = f;
    uint32_t r = c.i + 0x7FFFu + ((c.i >> 16) & 1u);
    return (unsigned short)(r >> 16);
}
static __device__ __forceinline__ void gl_lds16(const unsigned short* g, unsigned short* l) {
    __builtin_amdgcn_global_load_lds(
        (const __attribute__((address_space(1))) unsigned int*)(g),
        (__attribute__((address_space(3))) unsigned int*)(l), 16, 0, 0);
}

__global__ void k_eb(const float* __restrict__ pb, unsigned short* __restrict__ eb) {
    int i = blockIdx.x * 256 + threadIdx.x;
    float4 v = reinterpret_cast<const float4*>(pb)[i];
    union { unsigned short u[4]; uint2 p; } o;
    o.u[0] = f2b(__expf(v.x)); o.u[1] = f2b(__expf(v.y));
    o.u[2] = f2b(__expf(v.z)); o.u[3] = f2b(__expf(v.w));
    reinterpret_cast<uint2*>(eb)[i] = o.p;
}

__global__ void k_cvt(const float* __restrict__ src, unsigned short* __restrict__ dst) {
    int i = blockIdx.x * 256 + threadIdx.x;
    const float4* p = reinterpret_cast<const float4*>(src) + (size_t)i * 2;
    float4 f0 = p[0], f1 = p[1];
    union { unsigned short u[8]; int4 v; } o;
    o.u[0]=f2b(f0.x); o.u[1]=f2b(f0.y); o.u[2]=f2b(f0.z); o.u[3]=f2b(f0.w);
    o.u[4]=f2b(f1.x); o.u[5]=f2b(f1.y); o.u[6]=f2b(f1.z); o.u[7]=f2b(f1.w);
    reinterpret_cast<int4*>(dst)[i] = o.v;
}

__global__ void k_cvt_kv(const float* __restrict__ src, unsigned short* __restrict__ Wb,
                         int toff) {
    int i = blockIdx.x * 256 + threadIdx.x;
    int r = i >> 6, c8 = i & 63;
    const float4* p = reinterpret_cast<const float4*>(src + (size_t)r * DM + c8 * 8);
    float4 f0 = p[0], f1 = p[1];
    union { unsigned short u[8]; int4 v; } o;
    o.u[0]=f2b(f0.x); o.u[1]=f2b(f0.y); o.u[2]=f2b(f0.z); o.u[3]=f2b(f0.w);
    o.u[4]=f2b(f1.x); o.u[5]=f2b(f1.y); o.u[6]=f2b(f1.z); o.u[7]=f2b(f1.w);
    int r2 = 512 + ((r >> 6) << 7) + toff + (r & 63);
    *reinterpret_cast<int4*>(&Wb[(size_t)r2 * DM + c8 * 8]) = o.v;
}

// ---------------- shared pipelined K-loop (BK=32, 2 slots, 2 blocks/CU) ------
// LDS shorts: A slot s @ s*8192 ; B slot s @ 16384 + s*8192. NT = K/32 (even).
// Tile t: {stage A,B of t+1 into slot (t+1)&1 | read slot t&1 | 32 MFMA |
//          vmcnt(0) | barrier}. WAR: slot (t+1)&1's last reads were in tile
// t-1, sealed by bar(t-1) before the stage issues. RAW: vmcnt(0)+bar at end
// of t publishes t+1 to all waves. No garbage tail (stage skipped at t=NT-1).
template<int NT>
static __device__ __forceinline__ void gemm_p(
    const unsigned short* __restrict__ Abase,
    const unsigned short* __restrict__ Bbase,
    int lda, int ldb, unsigned short* smem, f32x4 (&acc)[8][4],
    int wave, int lane)
{
    const int wr = wave >> 2, wq = wave & 3;
    const int lrow = lane & 15, lkg = lane >> 4;
    const int po  = lane >> 3;                 // row-pair offset within wave's 8
    const int sub = (lane >> 2) & 1;
    const int qp  = lane & 3;                  // LDS 16B-slot within 64-short pair-row

    auto stage = [&](int mat, int s, int h, int t) {
        int p = h * 64 + wave * 8 + po;        // row-pair 0..127
        int r = p * 2 + sub;                   // tile row 0..255
        int q = qp ^ (p & 3);                  // inverse of read-side swizzle
        int col = (t << 5) + q * 8;
        const unsigned short* g = (mat ? Bbase + (size_t)r * ldb
                                       : Abase + (size_t)r * lda) + col;
        unsigned short* d = smem + mat * 16384 + s * 8192 + (h * 64 + wave * 8) * 64;
        gl_lds16(g, d);                        // lane lands at +lane*16B
    };
    auto loadA = [&](int s, int h, bf16x8* af) {
        const unsigned short* base = smem + s * 8192;
        #pragma unroll
        for (int mi = 0; mi < 4; ++mi) {
            int r = wr * 128 + h * 64 + mi * 16 + lrow;
            int p = r >> 1;
            af[mi] = *reinterpret_cast<const bf16x8*>(
                base + p * 64 + (r & 1) * 32 + ((lkg ^ (p & 3)) << 3));
        }
    };
    auto loadB = [&](int s, bf16x8* bf) {
        const unsigned short* base = smem + 16384 + s * 8192;
        #pragma unroll
        for (int ni = 0; ni < 4; ++ni) {
            int r = wq * 64 + ni * 16 + lrow;
            int p = r >> 1;
            bf[ni] = *reinterpret_cast<const bf16x8*>(
                base + p * 64 + (r & 1) * 32 + ((lkg ^ (p & 3)) << 3));
        }
    };
    auto mfma16 = [&](int h, bf16x8* af, bf16x8* bf) {
        __builtin_amdgcn_s_setprio(1);
        #pragma unroll
        for (int mi = 0; mi < 4; ++mi)
            #pragma unroll
            for (int ni = 0; ni < 4; ++ni)
                acc[h * 4 + mi][ni] = __builtin_amdgcn_mfma_f32_16x16x32_bf16(
                    af[mi], bf[ni], acc[h * 4 + mi][ni], 0, 0, 0);
        __builtin_amdgcn_s_setprio(0);
    };

    // prologue: stage tile 0 into slot 0, publish
    stage(0, 0, 0, 0); stage(0, 0, 1, 0);
    stage(1, 0, 0, 0); stage(1, 0, 1, 0);
    asm volatile("s_waitcnt vmcnt(0)" ::: "memory");
    __builtin_amdgcn_s_barrier();

    #pragma unroll 1
    for (int tt = 0; tt < NT; tt += 2) {
        #pragma unroll
        for (int u = 0; u < 2; ++u) {
            const int t = tt + u;
            const int s = u, sn = u ^ 1;
            if (t + 1 < NT) {                  // prefetch next tile first
                stage(0, sn, 0, t + 1); stage(0, sn, 1, t + 1);
                stage(1, sn, 0, t + 1); stage(1, sn, 1, t + 1);
            }
            bf16x8 af[4], bfr[4];
            loadB(s, bfr); loadA(s, 0, af);
            mfma16(0, af, bfr);
            loadA(s, 1, af);
            mfma16(1, af, bfr);
            asm volatile("s_waitcnt vmcnt(0)" ::: "memory");  // t+1 resident
            __builtin_amdgcn_s_barrier();
        }
    }
}

// ---------------- P1: fused QKV projection ----------------
// 1536 blocks = 256 mtiles x 6 etiles; XCD-chunked, etile fastest.
__launch_bounds__(512, 4)
__global__ void k_qkv(const unsigned short* __restrict__ xb,
                      const unsigned short* __restrict__ Wb,
                      const float* __restrict__ bq, const float* __restrict__ bk,
                      const float* __restrict__ bv,
                      unsigned short* __restrict__ s_out,
                      unsigned short* __restrict__ Z)
{
    extern __shared__ unsigned short smem[];          // 69632 B (gemm 64K, T 68K)
    const int bid = blockIdx.x;
    const int logical = (bid & 7) * 192 + (bid >> 3);
    const int mtile = logical / 6, etile = logical % 6;
    const int brow = mtile * 256;
    const int erow = etile * 256;
    const bool isq = (etile < 2);

    const int tid = threadIdx.x;
    const int lane = tid & 63, wave = tid >> 6;
    const int wr = wave >> 2, wq = wave & 3;
    const int lrow = lane & 15, lkg = lane >> 4;

    f32x4 acc[8][4];
    const f32x4 z4 = {0.f, 0.f, 0.f, 0.f};
    #pragma unroll
    for (int a = 0; a < 8; ++a)
        #pragma unroll
        for (int c = 0; c < 4; ++c) acc[a][c] = z4;

    gemm_p<16>(xb + (size_t)brow * DM, Wb + (size_t)erow * DM, DM, DM,
               smem, acc, wave, lane);

    unsigned short* T = smem;                          // [*][136] overlay
    if (isq) {
        const int ecol = etile * 256;
        #pragma unroll
        for (int pp = 0; pp < 2; ++pp) {
            __syncthreads();
            if ((wq >> 1) == pp) {
                #pragma unroll
                for (int mi = 0; mi < 8; ++mi) {
                    int m0 = wr*128 + mi*16 + lkg*4;
                    #pragma unroll
                    for (int ni = 0; ni < 4; ++ni) {
                        int nl = (wq & 1) * 64 + ni*16 + lrow;
                        float bia = bq[ecol + pp*128 + nl];
                        #pragma unroll
                        for (int r = 0; r < 4; ++r) {
                            float tq = acc[mi][ni][r] + bia;
                            float sg = __builtin_amdgcn_rcpf(1.f + __expf(-tq));
                            T[(m0 + r) * 136 + nl] = f2b(sg);
                        }
                    }
                }
            }
            __syncthreads();
            #pragma unroll
            for (int it = 0; it < 8; ++it) {
                int idx = it * 512 + tid;
                int m = idx >> 4, ng = idx & 15;
                int4 vv = *reinterpret_cast<const int4*>(&T[m * 136 + ng * 8]);
                *reinterpret_cast<int4*>(
                    &s_out[(size_t)(brow + m) * DM + ecol + pp*128 + ng * 8]) = vv;
            }
        }
    } else {
        const int gbase = (etile - 2) * 2;
        const int b = brow >> 10;
        #pragma unroll
        for (int pp = 0; pp < 2; ++pp) {              // m-half
            __syncthreads();
            if (wr == pp) {
                #pragma unroll
                for (int mi = 0; mi < 8; ++mi) {
                    int m0 = mi*16 + lkg*4;
                    #pragma unroll
                    for (int ni = 0; ni < 4; ++ni) {
                        int n = wq*64 + ni*16 + lrow;
                        int sub = (n >> 6) & 1, dr = n & 63;
                        int d = (gbase + (n >> 7)) * 64 + dr;
                        float bia = (sub == 0) ? bk[d] : bv[d];
                        union { unsigned short u[4]; uint2 p; } o;
                        #pragma unroll
                        for (int r = 0; r < 4; ++r) {
                            float tv = acc[mi][ni][r] + bia;
                            o.u[r] = f2b((sub == 0) ? __expf(tv) : tv);
                        }
                        *reinterpret_cast<uint2*>(&T[n * 136 + m0]) = o.p;
                    }
                }
            }
            __syncthreads();
            const int j0 = (brow & (NSEQ - 1)) + pp * 128;
            #pragma unroll
            for (int it = 0; it < 8; ++it) {
                int idx = it * 512 + tid;
                int zr = idx >> 4, jg = idx & 15;
                int gg = zr >> 7, sub2 = (zr >> 6) & 1, dr = zr & 63;
                int d = (gbase + gg) * 64 + dr;
                union { unsigned short u[8]; int4 v; } o;
                if (sub2 == 0) {
                    union { unsigned short u[8]; int4 v; } pe, pv;
                    pe.v = *reinterpret_cast<const int4*>(&T[(gg*128 + dr) * 136 + jg*8]);
                    pv.v = *reinterpret_cast<const int4*>(&T[(gg*128 + 64 + dr) * 136 + jg*8]);
                    #pragma unroll
                    for (int j = 0; j < 8; ++j) o.u[j] = f2b(b2f(pe.u[j]) * b2f(pv.u[j]));
                } else {
                    o.v = *reinterpret_cast<const int4*>(&T[(gg*128 + dr) * 136 + jg*8]);
                }
                int nn = ((d >> 4) << 5) + sub2 * 16 + (d & 15);
                size_t off = ((size_t)(b * NSEQ + nn)) * NSEQ + j0 + jg * 8;
                *reinterpret_cast<int4*>(&Z[off]) = o.v;
            }
        }
    }
}

// ---------------- P2: merged mixing GEMM ----------------
// 1024 blocks = 4 itiles x 256 ntiles, XCD-chunked, itile fastest.
__launch_bounds__(512, 4)
__global__ void k_aft(const unsigned short* __restrict__ eb,
                      const unsigned short* __restrict__ Z,
                      const unsigned short* __restrict__ s_in,
                      float* __restrict__ out)
{
    extern __shared__ unsigned short smem[];          // 65536 B
    const int bid = blockIdx.x;
    const int logical = (bid & 7) * 128 + (bid >> 3);
    const int itile = logical & 3, ntile = logical >> 2;
    const int i0 = itile * 256;
    const int n0 = ntile * 256;

    const int tid = threadIdx.x;
    const int lane = tid & 63, wave = tid >> 6;
    const int wr = wave >> 2, wq = wave & 3;
    const int lrow = lane & 15, lkg = lane >> 4;

    f32x4 acc[8][4];
    const f32x4 z4 = {0.f, 0.f, 0.f, 0.f};
    #pragma unroll
    for (int a = 0; a < 8; ++a)
        #pragma unroll
        for (int c = 0; c < 4; ++c) acc[a][c] = z4;

    gemm_p<32>(eb + (size_t)i0 * NSEQ, Z + (size_t)n0 * NSEQ, NSEQ, NSEQ,
               smem, acc, wave, lane);

    // epilogue: ni pairs (0,1),(2,3) are (num,den) for the same d
    #pragma unroll
    for (int mi = 0; mi < 8; ++mi) {
        int i = i0 + wr*128 + mi*16 + lkg*4;
        #pragma unroll
        for (int pi = 0; pi < 2; ++pi) {
            int nA = n0 + wq*64 + pi*32 + lrow;
            int b  = nA >> 10, nn = nA & (NSEQ - 1);
            int d  = ((nn >> 5) << 4) + (nn & 15);
            #pragma unroll
            for (int r = 0; r < 4; ++r) {
                size_t o = ((size_t)(b * NSEQ + i + r)) * DM + d;
                float num = acc[mi][pi*2][r];
                float den = acc[mi][pi*2 + 1][r];
                out[o] = b2f(s_in[o]) * num / den;
            }
        }
    }
}

extern "C" void kernel_launch(void* const* d_in, const int* in_sizes, int n_in,
                              void* d_out, int out_size, void* d_ws, size_t ws_size,
                              hipStream_t stream)
{
    const float* x  = (const float*)d_in[0];
    const float* Wq = (const float*)d_in[1];
    const float* bq = (const float*)d_in[2];
    const float* Wk = (const float*)d_in[3];
    const float* bk = (const float*)d_in[4];
    const float* Wv = (const float*)d_in[5];
    const float* bv = (const float*)d_in[6];
    const float* pb = (const float*)d_in[7];
    float* out = (float*)d_out;

    char* ws = (char*)d_ws;
    unsigned short* eb  = (unsigned short*)(ws);                          // 2 MiB
    unsigned short* Wb  = (unsigned short*)(ws + ((size_t)2   << 20));    // 1.5 MiB
    unsigned short* xb  = (unsigned short*)(ws + ((size_t)4   << 20));    // 64 MiB
    unsigned short* s   = (unsigned short*)(ws + ((size_t)68  << 20));    // 64 MiB
    unsigned short* Z   = (unsigned short*)(ws + ((size_t)132 << 20));    // 128 MiB

    k_eb <<<1024, 256, 0, stream>>>(pb, eb);
    k_cvt<<<16384, 256, 0, stream>>>(x,  xb);
    k_cvt<<<128,   256, 0, stream>>>(Wq, Wb);
    k_cvt_kv<<<128, 256, 0, stream>>>(Wk, Wb, 0);
    k_cvt_kv<<<128, 256, 0, stream>>>(Wv, Wb, 64);
    k_qkv<<<1536, 512, 69632, stream>>>(xb, Wb, bq, bk, bv, s, Z);
    k_aft<<<1024, 512, 65536, stream>>>(eb, Z, s, out);
}

// Round 10
// 359.678 us; speedup vs baseline: 6.3412x; 6.3412x over previous
//
#include <hip/hip_runtime.h>
#include <hip/hip_bf16.h>
#include <stdint.h>

// AFT-full, MI355X. Shapes: x[64,1024,512], W*[512,512], pos_bias[1024,1024].
//   q,k,v = x W^T + b ; out = sigmoid(q) * (eb@(e^k*v)) / (eb@e^k), eb=exp(pos_bias)
// Pipeline:
//   K0: eb = bf16(exp(pos_bias));  K1: xb = bf16(x), Wb = [Wq; Wk/Wv interleaved]
//   P1: fused QKV GEMM -> s (sigmoid(q), natural), Z (ekv/ek K-major interleaved)
//   P2: merged GEMM C[i,n] = eb @ Z^T, register-local num/den division epilogue.
// r10 = r9 with the launch-bounds bug fixed: __launch_bounds__(512) ONLY.
// r9's (512,4) forced a 64-VGPR cap -> the 128-VGPR accumulator spilled to
// scratch (5.9 GB/dispatch of scratch traffic, 8x regression). With no min-wave
// hint the compiler lands ~108 VGPR (r8-verified) <= 128, so the 64 KiB LDS
// gives 2 blocks/CU = 4 waves/SIMD naturally — the occupancy-2 hypothesis test.
// K-loop: 256x256 tile, BK=32, 8 waves, LDS = 2 slots (A+B) = 64 KiB. Per tile:
// {stage(t+1) first (8 gl_lds) | 12 ds_read | 32 MFMA | vmcnt(0) | barrier};
// prologue/epilogue exposure and the drain hide under the co-resident block.
// Paired-row LDS layout (bank-conflict-free, r7-verified): (r,c) at
// (r>>1)*64 + (r&1)*32 + ((c>>3)^((r>>1)&3))*8 shorts; stage pre-applies the
// inverse permutation on the global source (both-sides rule).
// Workspace: eb 2MiB@0, Wb 1.5MiB@2MiB, xb 64MiB@4MiB, s 64MiB@68MiB, Z 128MiB@132MiB.

#define NSEQ 1024
#define DM   512

typedef __attribute__((ext_vector_type(8))) short bf16x8;
typedef __attribute__((ext_vector_type(4))) float f32x4;

static __device__ __forceinline__ float b2f(unsigned short u) {
    union { uint32_t i; float f; } c; c.i = ((uint32_t)u) << 16; return c.f;
}
static __device__ __forceinline__ unsigned short f2b(float f) {
    union { float f; uint32_t i; } c; c.f = f;
    uint32_t r = c.i + 0x7FFFu + ((c.i >> 16) & 1u);
    return (unsigned short)(r >> 16);
}
static __device__ __forceinline__ void gl_lds16(const unsigned short* g, unsigned short* l) {
    __builtin_amdgcn_global_load_lds(
        (const __attribute__((address_space(1))) unsigned int*)(g),
        (__attribute__((address_space(3))) unsigned int*)(l), 16, 0, 0);
}

__global__ void k_eb(const float* __restrict__ pb, unsigned short* __restrict__ eb) {
    int i = blockIdx.x * 256 + threadIdx.x;
    float4 v = reinterpret_cast<const float4*>(pb)[i];
    union { unsigned short u[4]; uint2 p; } o;
    o.u[0] = f2b(__expf(v.x)); o.u[1] = f2b(__expf(v.y));
    o.u[2] = f2b(__expf(v.z)); o.u[3] = f2b(__expf(v.w));
    reinterpret_cast<uint2*>(eb)[i] = o.p;
}

__global__ void k_cvt(const float* __restrict__ src, unsigned short* __restrict__ dst) {
    int i = blockIdx.x * 256 + threadIdx.x;
    const float4* p = reinterpret_cast<const float4*>(src) + (size_t)i * 2;
    float4 f0 = p[0], f1 = p[1];
    union { unsigned short u[8]; int4 v; } o;
    o.u[0]=f2b(f0.x); o.u[1]=f2b(f0.y); o.u[2]=f2b(f0.z); o.u[3]=f2b(f0.w);
    o.u[4]=f2b(f1.x); o.u[5]=f2b(f1.y); o.u[6]=f2b(f1.z); o.u[7]=f2b(f1.w);
    reinterpret_cast<int4*>(dst)[i] = o.v;
}

__global__ void k_cvt_kv(const float* __restrict__ src, unsigned short* __restrict__ Wb,
                         int toff) {
    int i = blockIdx.x * 256 + threadIdx.x;
    int r = i >> 6, c8 = i & 63;
    const float4* p = reinterpret_cast<const float4*>(src + (size_t)r * DM + c8 * 8);
    float4 f0 = p[0], f1 = p[1];
    union { unsigned short u[8]; int4 v; } o;
    o.u[0]=f2b(f0.x); o.u[1]=f2b(f0.y); o.u[2]=f2b(f0.z); o.u[3]=f2b(f0.w);
    o.u[4]=f2b(f1.x); o.u[5]=f2b(f1.y); o.u[6]=f2b(f1.z); o.u[7]=f2b(f1.w);
    int r2 = 512 + ((r >> 6) << 7) + toff + (r & 63);
    *reinterpret_cast<int4*>(&Wb[(size_t)r2 * DM + c8 * 8]) = o.v;
}

// ---------------- shared pipelined K-loop (BK=32, 2 slots, 2 blocks/CU) ------
// LDS shorts: A slot s @ s*8192 ; B slot s @ 16384 + s*8192. NT = K/32 (even).
// Tile t: {stage A,B of t+1 into slot (t+1)&1 | read slot t&1 | 32 MFMA |
//          vmcnt(0) | barrier}. WAR: slot (t+1)&1's last reads were in tile
// t-1, sealed by bar(t-1) before the stage issues. RAW: vmcnt(0)+bar at end
// of t publishes t+1 to all waves. No garbage tail (stage skipped at t=NT-1).
template<int NT>
static __device__ __forceinline__ void gemm_p(
    const unsigned short* __restrict__ Abase,
    const unsigned short* __restrict__ Bbase,
    int lda, int ldb, unsigned short* smem, f32x4 (&acc)[8][4],
    int wave, int lane)
{
    const int wr = wave >> 2, wq = wave & 3;
    const int lrow = lane & 15, lkg = lane >> 4;
    const int po  = lane >> 3;                 // row-pair offset within wave's 8
    const int sub = (lane >> 2) & 1;
    const int qp  = lane & 3;                  // LDS 16B-slot within 64-short pair-row

    auto stage = [&](int mat, int s, int h, int t) {
        int p = h * 64 + wave * 8 + po;        // row-pair 0..127
        int r = p * 2 + sub;                   // tile row 0..255
        int q = qp ^ (p & 3);                  // inverse of read-side swizzle
        int col = (t << 5) + q * 8;
        const unsigned short* g = (mat ? Bbase + (size_t)r * ldb
                                       : Abase + (size_t)r * lda) + col;
        unsigned short* d = smem + mat * 16384 + s * 8192 + (h * 64 + wave * 8) * 64;
        gl_lds16(g, d);                        // lane lands at +lane*16B
    };
    auto loadA = [&](int s, int h, bf16x8* af) {
        const unsigned short* base = smem + s * 8192;
        #pragma unroll
        for (int mi = 0; mi < 4; ++mi) {
            int r = wr * 128 + h * 64 + mi * 16 + lrow;
            int p = r >> 1;
            af[mi] = *reinterpret_cast<const bf16x8*>(
                base + p * 64 + (r & 1) * 32 + ((lkg ^ (p & 3)) << 3));
        }
    };
    auto loadB = [&](int s, bf16x8* bf) {
        const unsigned short* base = smem + 16384 + s * 8192;
        #pragma unroll
        for (int ni = 0; ni < 4; ++ni) {
            int r = wq * 64 + ni * 16 + lrow;
            int p = r >> 1;
            bf[ni] = *reinterpret_cast<const bf16x8*>(
                base + p * 64 + (r & 1) * 32 + ((lkg ^ (p & 3)) << 3));
        }
    };
    auto mfma16 = [&](int h, bf16x8* af, bf16x8* bf) {
        __builtin_amdgcn_s_setprio(1);
        #pragma unroll
        for (int mi = 0; mi < 4; ++mi)
            #pragma unroll
            for (int ni = 0; ni < 4; ++ni)
                acc[h * 4 + mi][ni] = __builtin_amdgcn_mfma_f32_16x16x32_bf16(
                    af[mi], bf[ni], acc[h * 4 + mi][ni], 0, 0, 0);
        __builtin_amdgcn_s_setprio(0);
    };

    // prologue: stage tile 0 into slot 0, publish
    stage(0, 0, 0, 0); stage(0, 0, 1, 0);
    stage(1, 0, 0, 0); stage(1, 0, 1, 0);
    asm volatile("s_waitcnt vmcnt(0)" ::: "memory");
    __builtin_amdgcn_s_barrier();

    #pragma unroll 1
    for (int tt = 0; tt < NT; tt += 2) {
        #pragma unroll
        for (int u = 0; u < 2; ++u) {
            const int t = tt + u;
            const int s = u, sn = u ^ 1;
            if (t + 1 < NT) {                  // prefetch next tile first
                stage(0, sn, 0, t + 1); stage(0, sn, 1, t + 1);
                stage(1, sn, 0, t + 1); stage(1, sn, 1, t + 1);
            }
            bf16x8 af[4], bfr[4];
            loadB(s, bfr); loadA(s, 0, af);
            mfma16(0, af, bfr);
            loadA(s, 1, af);
            mfma16(1, af, bfr);
            asm volatile("s_waitcnt vmcnt(0)" ::: "memory");  // t+1 resident
            __builtin_amdgcn_s_barrier();
        }
    }
}

// ---------------- P1: fused QKV projection ----------------
// 1536 blocks = 256 mtiles x 6 etiles; XCD-chunked, etile fastest.
__launch_bounds__(512)
__global__ void k_qkv(const unsigned short* __restrict__ xb,
                      const unsigned short* __restrict__ Wb,
                      const float* __restrict__ bq, const float* __restrict__ bk,
                      const float* __restrict__ bv,
                      unsigned short* __restrict__ s_out,
                      unsigned short* __restrict__ Z)
{
    extern __shared__ unsigned short smem[];          // 69632 B (gemm 64K, T 68K)
    const int bid = blockIdx.x;
    const int logical = (bid & 7) * 192 + (bid >> 3);
    const int mtile = logical / 6, etile = logical % 6;
    const int brow = mtile * 256;
    const int erow = etile * 256;
    const bool isq = (etile < 2);

    const int tid = threadIdx.x;
    const int lane = tid & 63, wave = tid >> 6;
    const int wr = wave >> 2, wq = wave & 3;
    const int lrow = lane & 15, lkg = lane >> 4;

    f32x4 acc[8][4];
    const f32x4 z4 = {0.f, 0.f, 0.f, 0.f};
    #pragma unroll
    for (int a = 0; a < 8; ++a)
        #pragma unroll
        for (int c = 0; c < 4; ++c) acc[a][c] = z4;

    gemm_p<16>(xb + (size_t)brow * DM, Wb + (size_t)erow * DM, DM, DM,
               smem, acc, wave, lane);

    unsigned short* T = smem;                          // [*][136] overlay
    if (isq) {
        const int ecol = etile * 256;
        #pragma unroll
        for (int pp = 0; pp < 2; ++pp) {
            __syncthreads();
            if ((wq >> 1) == pp) {
                #pragma unroll
                for (int mi = 0; mi < 8; ++mi) {
                    int m0 = wr*128 + mi*16 + lkg*4;
                    #pragma unroll
                    for (int ni = 0; ni < 4; ++ni) {
                        int nl = (wq & 1) * 64 + ni*16 + lrow;
                        float bia = bq[ecol + pp*128 + nl];
                        #pragma unroll
                        for (int r = 0; r < 4; ++r) {
                            float tq = acc[mi][ni][r] + bia;
                            float sg = __builtin_amdgcn_rcpf(1.f + __expf(-tq));
                            T[(m0 + r) * 136 + nl] = f2b(sg);
                        }
                    }
                }
            }
            __syncthreads();
            #pragma unroll
            for (int it = 0; it < 8; ++it) {
                int idx = it * 512 + tid;
                int m = idx >> 4, ng = idx & 15;
                int4 vv = *reinterpret_cast<const int4*>(&T[m * 136 + ng * 8]);
                *reinterpret_cast<int4*>(
                    &s_out[(size_t)(brow + m) * DM + ecol + pp*128 + ng * 8]) = vv;
            }
        }
    } else {
        const int gbase = (etile - 2) * 2;
        const int b = brow >> 10;
        #pragma unroll
        for (int pp = 0; pp < 2; ++pp) {              // m-half
            __syncthreads();
            if (wr == pp) {
                #pragma unroll
                for (int mi = 0; mi < 8; ++mi) {
                    int m0 = mi*16 + lkg*4;
                    #pragma unroll
                    for (int ni = 0; ni < 4; ++ni) {
                        int n = wq*64 + ni*16 + lrow;
                        int sub = (n >> 6) & 1, dr = n & 63;
                        int d = (gbase + (n >> 7)) * 64 + dr;
                        float bia = (sub == 0) ? bk[d] : bv[d];
                        union { unsigned short u[4]; uint2 p; } o;
                        #pragma unroll
                        for (int r = 0; r < 4; ++r) {
                            float tv = acc[mi][ni][r] + bia;
                            o.u[r] = f2b((sub == 0) ? __expf(tv) : tv);
                        }
                        *reinterpret_cast<uint2*>(&T[n * 136 + m0]) = o.p;
                    }
                }
            }
            __syncthreads();
            const int j0 = (brow & (NSEQ - 1)) + pp * 128;
            #pragma unroll
            for (int it = 0; it < 8; ++it) {
                int idx = it * 512 + tid;
                int zr = idx >> 4, jg = idx & 15;
                int gg = zr >> 7, sub2 = (zr >> 6) & 1, dr = zr & 63;
                int d = (gbase + gg) * 64 + dr;
                union { unsigned short u[8]; int4 v; } o;
                if (sub2 == 0) {
                    union { unsigned short u[8]; int4 v; } pe, pv;
                    pe.v = *reinterpret_cast<const int4*>(&T[(gg*128 + dr) * 136 + jg*8]);
                    pv.v = *reinterpret_cast<const int4*>(&T[(gg*128 + 64 + dr) * 136 + jg*8]);
                    #pragma unroll
                    for (int j = 0; j < 8; ++j) o.u[j] = f2b(b2f(pe.u[j]) * b2f(pv.u[j]));
                } else {
                    o.v = *reinterpret_cast<const int4*>(&T[(gg*128 + dr) * 136 + jg*8]);
                }
                int nn = ((d >> 4) << 5) + sub2 * 16 + (d & 15);
                size_t off = ((size_t)(b * NSEQ + nn)) * NSEQ + j0 + jg * 8;
                *reinterpret_cast<int4*>(&Z[off]) = o.v;
            }
        }
    }
}

// ---------------- P2: merged mixing GEMM ----------------
// 1024 blocks = 4 itiles x 256 ntiles, XCD-chunked, itile fastest.
__launch_bounds__(512)
__global__ void k_aft(const unsigned short* __restrict__ eb,
                      const unsigned short* __restrict__ Z,
                      const unsigned short* __restrict__ s_in,
                      float* __restrict__ out)
{
    extern __shared__ unsigned short smem[];          // 65536 B
    const int bid = blockIdx.x;
    const int logical = (bid & 7) * 128 + (bid >> 3);
    const int itile = logical & 3, ntile = logical >> 2;
    const int i0 = itile * 256;
    const int n0 = ntile * 256;

    const int tid = threadIdx.x;
    const int lane = tid & 63, wave = tid >> 6;
    const int wr = wave >> 2, wq = wave & 3;
    const int lrow = lane & 15, lkg = lane >> 4;

    f32x4 acc[8][4];
    const f32x4 z4 = {0.f, 0.f, 0.f, 0.f};
    #pragma unroll
    for (int a = 0; a < 8; ++a)
        #pragma unroll
        for (int c = 0; c < 4; ++c) acc[a][c] = z4;

    gemm_p<32>(eb + (size_t)i0 * NSEQ, Z + (size_t)n0 * NSEQ, NSEQ, NSEQ,
               smem, acc, wave, lane);

    // epilogue: ni pairs (0,1),(2,3) are (num,den) for the same d
    #pragma unroll
    for (int mi = 0; mi < 8; ++mi) {
        int i = i0 + wr*128 + mi*16 + lkg*4;
        #pragma unroll
        for (int pi = 0; pi < 2; ++pi) {
            int nA = n0 + wq*64 + pi*32 + lrow;
            int b  = nA >> 10, nn = nA & (NSEQ - 1);
            int d  = ((nn >> 5) << 4) + (nn & 15);
            #pragma unroll
            for (int r = 0; r < 4; ++r) {
                size_t o = ((size_t)(b * NSEQ + i + r)) * DM + d;
                float num = acc[mi][pi*2][r];
                float den = acc[mi][pi*2 + 1][r];
                out[o] = b2f(s_in[o]) * num / den;
            }
        }
    }
}

extern "C" void kernel_launch(void* const* d_in, const int* in_sizes, int n_in,
                              void* d_out, int out_size, void* d_ws, size_t ws_size,
                              hipStream_t stream)
{
    const float* x  = (const float*)d_in[0];
    const float* Wq = (const float*)d_in[1];
    const float* bq = (const float*)d_in[2];
    const float* Wk = (const float*)d_in[3];
    const float* bk = (const float*)d_in[4];
    const float* Wv = (const float*)d_in[5];
    const float* bv = (const float*)d_in[6];
    const float* pb = (const float*)d_in[7];
    float* out = (float*)d_out;

    char* ws = (char*)d_ws;
    unsigned short* eb  = (unsigned short*)(ws);                          // 2 MiB
    unsigned short* Wb  = (unsigned short*)(ws + ((size_t)2   << 20));    // 1.5 MiB
    unsigned short* xb  = (unsigned short*)(ws + ((size_t)4   << 20));    // 64 MiB
    unsigned short* s   = (unsigned short*)(ws + ((size_t)68  << 20));    // 64 MiB
    unsigned short* Z   = (unsigned short*)(ws + ((size_t)132 << 20));    // 128 MiB

    k_eb <<<1024, 256, 0, stream>>>(pb, eb);
    k_cvt<<<16384, 256, 0, stream>>>(x,  xb);
    k_cvt<<<128,   256, 0, stream>>>(Wq, Wb);
    k_cvt_kv<<<128, 256, 0, stream>>>(Wk, Wb, 0);
    k_cvt_kv<<<128, 256, 0, stream>>>(Wv, Wb, 64);
    k_qkv<<<1536, 512, 69632, stream>>>(xb, Wb, bq, bk, bv, s, Z);
    k_aft<<<1024, 512, 65536, stream>>>(eb, Z, s, out);
}

// Round 11
// 343.976 us; speedup vs baseline: 6.6307x; 1.0456x over previous
//
#include <hip/hip_runtime.h>
#include <hip/hip_bf16.h>
#include <stdint.h>

// AFT-full, MI355X. Shapes: x[64,1024,512], W*[512,512], pos_bias[1024,1024].
//   q,k,v = x W^T + b ; out = sigmoid(q) * (eb@(e^k*v)) / (eb@e^k), eb=exp(pos_bias)
// Pipeline:
//   K0: eb = bf16(exp(pos_bias));  K1: xb = bf16(x), Wb = [Wq; Wk/Wv interleaved]
//   P1: fused QKV GEMM -> s (sigmoid(q), natural), Z (ekv/ek K-major interleaved)
//   P2: merged GEMM C[i,n] = eb @ Z^T, register-local num/den division epilogue.
// r11: faithful m201 8-phase schedule. 256x256 tile, BK=64, 8 waves, 128 KiB LDS
// = 2 K-tile buffers x 2 K-halves (kk0/kk1, 16 KB) x {A,B}. Phase (tile,kk,h) =
// {ds_read frags | stage 1 K-half (2 gl_lds) | barrier | setprio+16 MFMA |
// barrier}; vmcnt(4) ONLY at phases 4 and 8 (counted, never 0 in-loop).
// Ledger (iter i, T=2i, U=2i+1; buf d = tile parity):
//   ph1(T,k0,h0)|stgA(U,k1)  ph2(T,k0,h1)|stgB(U,k1)
//   ph3(T,k1,h0)|stgA(T+2,k0) ph4(T,k1,h1)|stgB(T+2,k0)+vmcnt(4)
//   ph5(U,k0,h0)|stgA(T+2,k1) ph6(U,k0,h1)|stgB(T+2,k1)
//   ph7(U,k1,h0)|stgA(T+3,k0) ph8(U,k1,h1)|stgB(T+3,k0)+vmcnt(4)
// WAR: every stage target's last read is >=1 end-barrier earlier (K-half
// lifetimes end 2 phases early). RAW: ph4's vmcnt(4) forces prev ph7-8 (U k0,
// read ph5) and cur ph1-2 (U k1, read ph7); ph8's forces cur ph3-6 (T+2, read
// next ph1/ph3). Prologue: t0k0,t0k1,t1k0 + vmcnt(4). Tail stages wrapped
// garbage (uniform counts); vmcnt(0)+bar after loop.
// Paired-row LDS half [256r][32c] (r7-verified 0 conflicts): (r,c) at
// p*64+(r&1)*32+((c>>3)^(p&3))*8 shorts, p=r>>1; stage pre-swizzles global src.
// Workspace: eb 2MiB@0, Wb 1.5MiB@2MiB, xb 64MiB@4MiB, s 64MiB@68MiB, Z 128MiB@132MiB.

#define NSEQ 1024
#define DM   512

typedef __attribute__((ext_vector_type(8))) short bf16x8;
typedef __attribute__((ext_vector_type(4))) float f32x4;

static __device__ __forceinline__ float b2f(unsigned short u) {
    union { uint32_t i; float f; } c; c.i = ((uint32_t)u) << 16; return c.f;
}
static __device__ __forceinline__ unsigned short f2b(float f) {
    union { float f; uint32_t i; } c; c.f = f;
    uint32_t r = c.i + 0x7FFFu + ((c.i >> 16) & 1u);
    return (unsigned short)(r >> 16);
}
static __device__ __forceinline__ void gl_lds16(const unsigned short* g, unsigned short* l) {
    __builtin_amdgcn_global_load_lds(
        (const __attribute__((address_space(1))) unsigned int*)(g),
        (__attribute__((address_space(3))) unsigned int*)(l), 16, 0, 0);
}

#define PH_BAR() do { asm volatile("" ::: "memory"); \
    __builtin_amdgcn_s_barrier(); asm volatile("" ::: "memory"); } while (0)

__global__ void k_eb(const float* __restrict__ pb, unsigned short* __restrict__ eb) {
    int i = blockIdx.x * 256 + threadIdx.x;
    float4 v = reinterpret_cast<const float4*>(pb)[i];
    union { unsigned short u[4]; uint2 p; } o;
    o.u[0] = f2b(__expf(v.x)); o.u[1] = f2b(__expf(v.y));
    o.u[2] = f2b(__expf(v.z)); o.u[3] = f2b(__expf(v.w));
    reinterpret_cast<uint2*>(eb)[i] = o.p;
}

__global__ void k_cvt(const float* __restrict__ src, unsigned short* __restrict__ dst) {
    int i = blockIdx.x * 256 + threadIdx.x;
    const float4* p = reinterpret_cast<const float4*>(src) + (size_t)i * 2;
    float4 f0 = p[0], f1 = p[1];
    union { unsigned short u[8]; int4 v; } o;
    o.u[0]=f2b(f0.x); o.u[1]=f2b(f0.y); o.u[2]=f2b(f0.z); o.u[3]=f2b(f0.w);
    o.u[4]=f2b(f1.x); o.u[5]=f2b(f1.y); o.u[6]=f2b(f1.z); o.u[7]=f2b(f1.w);
    reinterpret_cast<int4*>(dst)[i] = o.v;
}

__global__ void k_cvt_kv(const float* __restrict__ src, unsigned short* __restrict__ Wb,
                         int toff) {
    int i = blockIdx.x * 256 + threadIdx.x;
    int r = i >> 6, c8 = i & 63;
    const float4* p = reinterpret_cast<const float4*>(src + (size_t)r * DM + c8 * 8);
    float4 f0 = p[0], f1 = p[1];
    union { unsigned short u[8]; int4 v; } o;
    o.u[0]=f2b(f0.x); o.u[1]=f2b(f0.y); o.u[2]=f2b(f0.z); o.u[3]=f2b(f0.w);
    o.u[4]=f2b(f1.x); o.u[5]=f2b(f1.y); o.u[6]=f2b(f1.z); o.u[7]=f2b(f1.w);
    int r2 = 512 + ((r >> 6) << 7) + toff + (r & 63);
    *reinterpret_cast<int4*>(&Wb[(size_t)r2 * DM + c8 * 8]) = o.v;
}

// ---------------- shared 8-phase K-loop (BK=64, 2 bufs x 2 K-halves) ---------
// LDS shorts: A half(d,c) @ (d*2+c)*8192 ; B half(d,c) @ 32768 + (d*2+c)*8192.
template<int NT>   // NT = K/64, even
static __device__ __forceinline__ void gemm8(
    const unsigned short* __restrict__ Abase,
    const unsigned short* __restrict__ Bbase,
    int lda, int ldb, unsigned short* smem, f32x4 (&acc)[8][4],
    int wave, int lane)
{
    const int wr = wave >> 2, wq = wave & 3;
    const int lrow = lane & 15, lkg = lane >> 4;
    const int po = lane >> 3, sub = (lane >> 2) & 1, qp = lane & 3;
    const int ch0 = wave * 2;

    auto half = [&](int isB, int d, int c) -> unsigned short* {
        return smem + isB * 32768 + (d * 2 + c) * 8192;
    };
    auto stg = [&](int isB, int d, int c, int t) {
        const unsigned short* gb = isB ? Bbase : Abase;
        const int ld = isB ? ldb : lda;
        unsigned short* dst = half(isB, d, c);
        #pragma unroll
        for (int q2 = 0; q2 < 2; ++q2) {
            int ch = ch0 + q2;
            int p = ch * 8 + po, r = p * 2 + sub;
            int col = ((t & (NT - 1)) << 6) + (c << 5) + ((qp ^ (p & 3)) << 3);
            gl_lds16(gb + (size_t)r * ld + col, dst + ch * 512);
        }
    };
    auto ldA = [&](int d, int c, int h, bf16x8* af) {
        const unsigned short* base = half(0, d, c);
        #pragma unroll
        for (int mi = 0; mi < 4; ++mi) {
            int r = wr * 128 + h * 64 + mi * 16 + lrow, p = r >> 1;
            af[mi] = *reinterpret_cast<const bf16x8*>(
                base + p * 64 + (r & 1) * 32 + ((lkg ^ (p & 3)) << 3));
        }
    };
    auto ldB = [&](int d, int c, bf16x8* bf) {
        const unsigned short* base = half(1, d, c);
        #pragma unroll
        for (int ni = 0; ni < 4; ++ni) {
            int r = wq * 64 + ni * 16 + lrow, p = r >> 1;
            bf[ni] = *reinterpret_cast<const bf16x8*>(
                base + p * 64 + (r & 1) * 32 + ((lkg ^ (p & 3)) << 3));
        }
    };
    auto mm = [&](int h, bf16x8* af, bf16x8* bf) {
        __builtin_amdgcn_s_setprio(1);
        #pragma unroll
        for (int mi = 0; mi < 4; ++mi)
            #pragma unroll
            for (int ni = 0; ni < 4; ++ni)
                acc[h * 4 + mi][ni] = __builtin_amdgcn_mfma_f32_16x16x32_bf16(
                    af[mi], bf[ni], acc[h * 4 + mi][ni], 0, 0, 0);
        __builtin_amdgcn_s_setprio(0);
    };

    // prologue: t0 k0, t0 k1, t1 k0 (12 loads); vmcnt(4) forces all of t0
    stg(0, 0, 0, 0); stg(1, 0, 0, 0);
    stg(0, 0, 1, 0); stg(1, 0, 1, 0);
    stg(0, 1, 0, 1); stg(1, 1, 0, 1);
    asm volatile("s_waitcnt vmcnt(4)" ::: "memory");
    __builtin_amdgcn_s_barrier();
    asm volatile("" ::: "memory");

    #pragma unroll 1
    for (int i = 0; i < NT / 2; ++i) {
        const int U = 2 * i + 1, T2 = 2 * i + 2, U2 = 2 * i + 3;
        bf16x8 af[4], bf[4];
        // ph1 (T,k0,h0) | stage A(U,k1)
        ldB(0, 0, bf); ldA(0, 0, 0, af); stg(0, 1, 1, U);
        PH_BAR(); mm(0, af, bf); PH_BAR();
        // ph2 (T,k0,h1) | stage B(U,k1)
        ldA(0, 0, 1, af); stg(1, 1, 1, U);
        PH_BAR(); mm(1, af, bf); PH_BAR();
        // ph3 (T,k1,h0) | stage A(T+2,k0)
        ldB(0, 1, bf); ldA(0, 1, 0, af); stg(0, 0, 0, T2);
        PH_BAR(); mm(0, af, bf); PH_BAR();
        // ph4 (T,k1,h1) | stage B(T+2,k0) | counted wait
        ldA(0, 1, 1, af); stg(1, 0, 0, T2);
        asm volatile("s_waitcnt vmcnt(4)" ::: "memory");
        PH_BAR(); mm(1, af, bf); PH_BAR();
        // ph5 (U,k0,h0) | stage A(T+2,k1)
        ldB(1, 0, bf); ldA(1, 0, 0, af); stg(0, 0, 1, T2);
        PH_BAR(); mm(0, af, bf); PH_BAR();
        // ph6 (U,k0,h1) | stage B(T+2,k1)
        ldA(1, 0, 1, af); stg(1, 0, 1, T2);
        PH_BAR(); mm(1, af, bf); PH_BAR();
        // ph7 (U,k1,h0) | stage A(T+3,k0)
        ldB(1, 1, bf); ldA(1, 1, 0, af); stg(0, 1, 0, U2);
        PH_BAR(); mm(0, af, bf); PH_BAR();
        // ph8 (U,k1,h1) | stage B(T+3,k0) | counted wait
        ldA(1, 1, 1, af); stg(1, 1, 0, U2);
        asm volatile("s_waitcnt vmcnt(4)" ::: "memory");
        PH_BAR(); mm(1, af, bf); PH_BAR();
    }
    asm volatile("s_waitcnt vmcnt(0)" ::: "memory");   // drain garbage tail
    __builtin_amdgcn_s_barrier();
    asm volatile("" ::: "memory");
}

// ---------------- P1: fused QKV projection ----------------
// 1536 blocks = 256 mtiles x 6 etiles; XCD-chunked, etile fastest.
__launch_bounds__(512)
__global__ void k_qkv(const unsigned short* __restrict__ xb,
                      const unsigned short* __restrict__ Wb,
                      const float* __restrict__ bq, const float* __restrict__ bk,
                      const float* __restrict__ bv,
                      unsigned short* __restrict__ s_out,
                      unsigned short* __restrict__ Z)
{
    extern __shared__ unsigned short smem[];          // 131072 B
    const int bid = blockIdx.x;
    const int logical = (bid & 7) * 192 + (bid >> 3);
    const int mtile = logical / 6, etile = logical % 6;
    const int brow = mtile * 256;
    const int erow = etile * 256;
    const bool isq = (etile < 2);

    const int tid = threadIdx.x;
    const int lane = tid & 63, wave = tid >> 6;
    const int wr = wave >> 2, wq = wave & 3;
    const int lrow = lane & 15, lkg = lane >> 4;

    f32x4 acc[8][4];
    const f32x4 z4 = {0.f, 0.f, 0.f, 0.f};
    #pragma unroll
    for (int a = 0; a < 8; ++a)
        #pragma unroll
        for (int c = 0; c < 4; ++c) acc[a][c] = z4;

    gemm8<8>(xb + (size_t)brow * DM, Wb + (size_t)erow * DM, DM, DM,
             smem, acc, wave, lane);

    unsigned short* T = smem;                          // [*][136] overlay
    if (isq) {
        const int ecol = etile * 256;
        #pragma unroll
        for (int pp = 0; pp < 2; ++pp) {
            __syncthreads();
            if ((wq >> 1) == pp) {
                #pragma unroll
                for (int mi = 0; mi < 8; ++mi) {
                    int m0 = wr*128 + mi*16 + lkg*4;
                    #pragma unroll
                    for (int ni = 0; ni < 4; ++ni) {
                        int nl = (wq & 1) * 64 + ni*16 + lrow;
                        float bia = bq[ecol + pp*128 + nl];
                        #pragma unroll
                        for (int r = 0; r < 4; ++r) {
                            float tq = acc[mi][ni][r] + bia;
                            float sg = __builtin_amdgcn_rcpf(1.f + __expf(-tq));
                            T[(m0 + r) * 136 + nl] = f2b(sg);
                        }
                    }
                }
            }
            __syncthreads();
            #pragma unroll
            for (int it = 0; it < 8; ++it) {
                int idx = it * 512 + tid;
                int m = idx >> 4, ng = idx & 15;
                int4 vv = *reinterpret_cast<const int4*>(&T[m * 136 + ng * 8]);
                *reinterpret_cast<int4*>(
                    &s_out[(size_t)(brow + m) * DM + ecol + pp*128 + ng * 8]) = vv;
            }
        }
    } else {
        const int gbase = (etile - 2) * 2;
        const int b = brow >> 10;
        #pragma unroll
        for (int pp = 0; pp < 2; ++pp) {              // m-half
            __syncthreads();
            if (wr == pp) {
                #pragma unroll
                for (int mi = 0; mi < 8; ++mi) {
                    int m0 = mi*16 + lkg*4;
                    #pragma unroll
                    for (int ni = 0; ni < 4; ++ni) {
                        int n = wq*64 + ni*16 + lrow;
                        int sub = (n >> 6) & 1, dr = n & 63;
                        int d = (gbase + (n >> 7)) * 64 + dr;
                        float bia = (sub == 0) ? bk[d] : bv[d];
                        union { unsigned short u[4]; uint2 p; } o;
                        #pragma unroll
                        for (int r = 0; r < 4; ++r) {
                            float tv = acc[mi][ni][r] + bia;
                            o.u[r] = f2b((sub == 0) ? __expf(tv) : tv);
                        }
                        *reinterpret_cast<uint2*>(&T[n * 136 + m0]) = o.p;
                    }
                }
            }
            __syncthreads();
            const int j0 = (brow & (NSEQ - 1)) + pp * 128;
            #pragma unroll
            for (int it = 0; it < 8; ++it) {
                int idx = it * 512 + tid;
                int zr = idx >> 4, jg = idx & 15;
                int gg = zr >> 7, sub2 = (zr >> 6) & 1, dr = zr & 63;
                int d = (gbase + gg) * 64 + dr;
                union { unsigned short u[8]; int4 v; } o;
                if (sub2 == 0) {
                    union { unsigned short u[8]; int4 v; } pe, pv;
                    pe.v = *reinterpret_cast<const int4*>(&T[(gg*128 + dr) * 136 + jg*8]);
                    pv.v = *reinterpret_cast<const int4*>(&T[(gg*128 + 64 + dr) * 136 + jg*8]);
                    #pragma unroll
                    for (int j = 0; j < 8; ++j) o.u[j] = f2b(b2f(pe.u[j]) * b2f(pv.u[j]));
                } else {
                    o.v = *reinterpret_cast<const int4*>(&T[(gg*128 + dr) * 136 + jg*8]);
                }
                int nn = ((d >> 4) << 5) + sub2 * 16 + (d & 15);
                size_t off = ((size_t)(b * NSEQ + nn)) * NSEQ + j0 + jg * 8;
                *reinterpret_cast<int4*>(&Z[off]) = o.v;
            }
        }
    }
}

// ---------------- P2: merged mixing GEMM ----------------
// 1024 blocks = 4 itiles x 256 ntiles, XCD-chunked, itile fastest.
__launch_bounds__(512)
__global__ void k_aft(const unsigned short* __restrict__ eb,
                      const unsigned short* __restrict__ Z,
                      const unsigned short* __restrict__ s_in,
                      float* __restrict__ out)
{
    extern __shared__ unsigned short smem[];          // 131072 B
    const int bid = blockIdx.x;
    const int logical = (bid & 7) * 128 + (bid >> 3);
    const int itile = logical & 3, ntile = logical >> 2;
    const int i0 = itile * 256;
    const int n0 = ntile * 256;

    const int tid = threadIdx.x;
    const int lane = tid & 63, wave = tid >> 6;
    const int wr = wave >> 2, wq = wave & 3;
    const int lrow = lane & 15, lkg = lane >> 4;

    f32x4 acc[8][4];
    const f32x4 z4 = {0.f, 0.f, 0.f, 0.f};
    #pragma unroll
    for (int a = 0; a < 8; ++a)
        #pragma unroll
        for (int c = 0; c < 4; ++c) acc[a][c] = z4;

    gemm8<16>(eb + (size_t)i0 * NSEQ, Z + (size_t)n0 * NSEQ, NSEQ, NSEQ,
              smem, acc, wave, lane);

    // epilogue: ni pairs (0,1),(2,3) are (num,den) for the same d
    #pragma unroll
    for (int mi = 0; mi < 8; ++mi) {
        int i = i0 + wr*128 + mi*16 + lkg*4;
        #pragma unroll
        for (int pi = 0; pi < 2; ++pi) {
            int nA = n0 + wq*64 + pi*32 + lrow;
            int b  = nA >> 10, nn = nA & (NSEQ - 1);
            int d  = ((nn >> 5) << 4) + (nn & 15);
            #pragma unroll
            for (int r = 0; r < 4; ++r) {
                size_t o = ((size_t)(b * NSEQ + i + r)) * DM + d;
                float num = acc[mi][pi*2][r];
                float den = acc[mi][pi*2 + 1][r];
                out[o] = b2f(s_in[o]) * num / den;
            }
        }
    }
}

extern "C" void kernel_launch(void* const* d_in, const int* in_sizes, int n_in,
                              void* d_out, int out_size, void* d_ws, size_t ws_size,
                              hipStream_t stream)
{
    const float* x  = (const float*)d_in[0];
    const float* Wq = (const float*)d_in[1];
    const float* bq = (const float*)d_in[2];
    const float* Wk = (const float*)d_in[3];
    const float* bk = (const float*)d_in[4];
    const float* Wv = (const float*)d_in[5];
    const float* bv = (const float*)d_in[6];
    const float* pb = (const float*)d_in[7];
    float* out = (float*)d_out;

    char* ws = (char*)d_ws;
    unsigned short* eb  = (unsigned short*)(ws);                          // 2 MiB
    unsigned short* Wb  = (unsigned short*)(ws + ((size_t)2   << 20));    // 1.5 MiB
    unsigned short* xb  = (unsigned short*)(ws + ((size_t)4   << 20));    // 64 MiB
    unsigned short* s   = (unsigned short*)(ws + ((size_t)68  << 20));    // 64 MiB
    unsigned short* Z   = (unsigned short*)(ws + ((size_t)132 << 20));    // 128 MiB

    k_eb <<<1024, 256, 0, stream>>>(pb, eb);
    k_cvt<<<16384, 256, 0, stream>>>(x,  xb);
    k_cvt<<<128,   256, 0, stream>>>(Wq, Wb);
    k_cvt_kv<<<128, 256, 0, stream>>>(Wk, Wb, 0);
    k_cvt_kv<<<128, 256, 0, stream>>>(Wv, Wb, 64);
    k_qkv<<<1536, 512, 131072, stream>>>(xb, Wb, bq, bk, bv, s, Z);
    k_aft<<<1024, 512, 131072, stream>>>(eb, Z, s, out);
}